// Round 5
// baseline (440.225 us; speedup 1.0000x reference)
//
#include <hip/hip_runtime.h>
#include <cstdint>
#include <cstddef>

// x = x556 + x570 (fp32 [12544,1024]); LayerNorm over C=1024; y = xn @ W^T + b
// (W [4096,1024] fp32, row-major = B^T GEMM layout); out = gelu(y), fp32.
// Internal compute: bf16 MFMA 32x32x16; tanh-form GELU (|err| vs erf ~1e-3 << 6.4e-2 thr).
#define M_DIM 12544
#define K_DIM 1024
#define N_DIM 4096

typedef __bf16 bf16x8 __attribute__((ext_vector_type(8)));
typedef float f32x16 __attribute__((ext_vector_type(16)));

#define VMCNT(n)  asm volatile("s_waitcnt vmcnt(" #n ")" ::: "memory")
#define LGKM(n)   asm volatile("s_waitcnt lgkmcnt(" #n ")" ::: "memory")
#define FENCE()   asm volatile("" ::: "memory")
#define SCHED0()  __builtin_amdgcn_sched_barrier(0)
#define BAR()     __builtin_amdgcn_s_barrier()

__device__ __forceinline__ unsigned short bf16_rne(float f) {
    unsigned int u = __float_as_uint(f);
    u += 0x7FFFu + ((u >> 16) & 1u);
    return (unsigned short)(u >> 16);
}
__device__ __forceinline__ unsigned int pack2_bf16(float lo, float hi) {
    return (unsigned int)bf16_rne(lo) | ((unsigned int)bf16_rne(hi) << 16);
}
// tanh-form GELU: x * sigmoid(1.5957691*x*(1+0.044715 x^2)); ~8 VALU ops vs erff's ~25.
__device__ __forceinline__ float gelu_fast(float x) {
    float t = 1.5957691216057308f * x * fmaf(0.044715f, x * x, 1.0f);
    float e = __expf(-t);                       // v_exp_f32
    return x * __builtin_amdgcn_rcpf(1.0f + e); // v_rcp_f32
}

// async global->LDS, 16B per lane. LDS dest must be wave-uniform base + lane*16.
__device__ __forceinline__ void async_load16(const void* g, void* l) {
    __builtin_amdgcn_global_load_lds(
        (const __attribute__((address_space(1))) void*)g,
        (__attribute__((address_space(3))) void*)l,
        16, 0, 0);
}

// -------- fused: residual add + LayerNorm -> bf16 xn  AND  W fp32 -> bf16 ----
// blocks [0,3136): LN rows (4 rows/block). blocks [3136,4160): W convert.
__global__ __launch_bounds__(256) void pre_fused(
    const float* __restrict__ x0,
    const float* __restrict__ x1,
    const float* __restrict__ gam,
    const float* __restrict__ bet,
    const float* __restrict__ Wlin,
    unsigned short* __restrict__ o,
    unsigned short* __restrict__ wb)
{
    const int bid = blockIdx.x;
    if (bid >= M_DIM / 4) {
        const int wbid = bid - M_DIM / 4;
        const float* wp = Wlin + (size_t)wbid * 4096;
        unsigned short* op = wb + (size_t)wbid * 4096;
        #pragma unroll
        for (int j = 0; j < 4; ++j) {
            float4 v = *(const float4*)(wp + j * 1024 + threadIdx.x * 4);
            uint2 r;
            r.x = pack2_bf16(v.x, v.y);
            r.y = pack2_bf16(v.z, v.w);
            *(uint2*)(op + j * 1024 + threadIdx.x * 4) = r;
        }
        return;
    }

    const int lane = threadIdx.x & 63;
    const int wv   = threadIdx.x >> 6;
    const size_t row = (size_t)bid * 4 + wv;
    const float* p0 = x0 + row * K_DIM;
    const float* p1 = x1 + row * K_DIM;

    float v[16];
    #pragma unroll
    for (int i = 0; i < 4; ++i) {
        float4 a = *(const float4*)(p0 + i * 256 + lane * 4);
        float4 b = *(const float4*)(p1 + i * 256 + lane * 4);
        v[4*i+0] = a.x + b.x; v[4*i+1] = a.y + b.y;
        v[4*i+2] = a.z + b.z; v[4*i+3] = a.w + b.w;
    }

    float s = 0.f, sq = 0.f;
    #pragma unroll
    for (int i = 0; i < 16; ++i) { s += v[i]; sq += v[i] * v[i]; }
    #pragma unroll
    for (int m = 32; m >= 1; m >>= 1) {
        s  += __shfl_xor(s,  m);
        sq += __shfl_xor(sq, m);
    }
    const float mean = s * (1.0f / 1024.0f);
    float var = sq * (1.0f / 1024.0f) - mean * mean;
    var = fmaxf(var, 0.0f);
    const float rstd = rsqrtf(var + 1e-5f);

    unsigned short* po = o + row * K_DIM;
    #pragma unroll
    for (int i = 0; i < 4; ++i) {
        float4 g  = *(const float4*)(gam + i * 256 + lane * 4);
        float4 be = *(const float4*)(bet + i * 256 + lane * 4);
        float y0 = (v[4*i+0] - mean) * rstd * g.x + be.x;
        float y1 = (v[4*i+1] - mean) * rstd * g.y + be.y;
        float y2 = (v[4*i+2] - mean) * rstd * g.z + be.z;
        float y3 = (v[4*i+3] - mean) * rstd * g.w + be.w;
        uint2 r;
        r.x = pack2_bf16(y0, y1);
        r.y = pack2_bf16(y2, y3);
        *(uint2*)(po + i * 256 + lane * 4) = r;
    }
}

// ---------------- GEMM: C[M,N] = gelu(A[M,K] @ B[N,K]^T + bias) ----------------
// 256x256 tile, BK=64, 512 threads = 8 waves (2Mx4N), per-wave 128x64 output.
// FINE 4-PHASE SCHEDULE (m201-style), one phase per k-slice (ks):
//   phase p: { issue 6 ds_reads for ks=p+1 into the other frag set
//              || stage 4 of next tile's 8 loads (A@p0, B@p1) }
//            BAR; s_waitcnt lgkmcnt(6)   <- drains ONLY the PREVIOUS phase's
//                                           reads (counted lgkm, T4 analog);
//            setprio(1); 8 MFMA on prev set; setprio(0); BAR.
// LDS latency of each phase's reads hides under the other SIMD-wave's MFMA
// cluster + barrier span; setprio arbitrates the role-split (T5).
// Tile boundary (p3): VMCNT(0) is counted-exact (only next tile's 8 loads are
// outstanding, issued 2-3 phases earlier) + BAR, then read-ahead ks0 from the
// other buffer. Slot reuse safe: buf c's last reads drain at p3's lgkmcnt
// before the closing BAR that precedes any restage into it.
__global__ __launch_bounds__(512, 2) void gemm_bias_gelu(
    const unsigned short* __restrict__ A,    // xn [M,K] bf16
    const unsigned short* __restrict__ B,    // W  [N,K] bf16
    const float* __restrict__ bias,          // [N] fp32
    float* __restrict__ C)                   // [M,N] fp32
{
    __shared__ __align__(16) unsigned short At[2][256 * 64];
    __shared__ __align__(16) unsigned short Bt[2][256 * 64];

    const int t  = threadIdx.x;          // 0..511
    const int bm = blockIdx.x;           // 0..48  (fast-varying -> same-bn blocks
    const int bn = blockIdx.y;           // 0..15   share one XCD's L2 B-panel)
    const int m0 = bm * 256, n0 = bn * 256;

    // staging: round r, thread t -> LDS elems r*4096 + t*8 (row r*64 + (t>>3),
    // phys seg t&7); global lseg = (pseg - (row&7)) & 7  [period-8 swizzle]
    const int srow = t >> 3;
    const int lseg = ((t & 7) - (srow & 7)) & 7;
    const unsigned short* ag0 = A + (size_t)(m0 + srow      ) * K_DIM + lseg * 8;
    const unsigned short* ag1 = A + (size_t)(m0 + srow +  64) * K_DIM + lseg * 8;
    const unsigned short* ag2 = A + (size_t)(m0 + srow + 128) * K_DIM + lseg * 8;
    const unsigned short* ag3 = A + (size_t)(m0 + srow + 192) * K_DIM + lseg * 8;
    const unsigned short* bg0 = B + (size_t)(n0 + srow      ) * K_DIM + lseg * 8;
    const unsigned short* bg1 = B + (size_t)(n0 + srow +  64) * K_DIM + lseg * 8;
    const unsigned short* bg2 = B + (size_t)(n0 + srow + 128) * K_DIM + lseg * 8;
    const unsigned short* bg3 = B + (size_t)(n0 + srow + 192) * K_DIM + lseg * 8;

    const int lane = t & 63;
    const int wid  = t >> 6;
    const int wr   = wid >> 2;           // 0..1: rows wr*128..+128
    const int wc   = wid & 3;            // 0..3: cols wc*64..+64
    const int ml   = lane & 31;
    const int h    = lane >> 5;

    f32x16 acc[4][2] = {};

    auto stageA = [&](int s) {
        async_load16(ag0, &At[s][        t * 8]);
        async_load16(ag1, &At[s][ 4096 + t * 8]);
        async_load16(ag2, &At[s][ 8192 + t * 8]);
        async_load16(ag3, &At[s][12288 + t * 8]);
        ag0 += 64; ag1 += 64; ag2 += 64; ag3 += 64;
        FENCE();
    };
    auto stageB = [&](int s) {
        async_load16(bg0, &Bt[s][        t * 8]);
        async_load16(bg1, &Bt[s][ 4096 + t * 8]);
        async_load16(bg2, &Bt[s][ 8192 + t * 8]);
        async_load16(bg3, &Bt[s][12288 + t * 8]);
        bg0 += 64; bg1 += 64; bg2 += 64; bg3 += 64;
        FENCE();
    };

    // fragment sets: 4 A + 2 B b128 reads, phys seg = (ks*2+h + (row&7)) & 7
    bf16x8 a0[4], b0[2], a1[4], b1[2];
    auto dsr = [&](int ks, int c, bf16x8* aS, bf16x8* bS) {
        #pragma unroll
        for (int i = 0; i < 4; ++i) {
            const int ra = wr * 128 + i * 32 + ml;
            aS[i] = *(const bf16x8*)&At[c][ra * 64 + ((((ks * 2 + h) + (ra & 7)) & 7) * 8)];
        }
        #pragma unroll
        for (int j = 0; j < 2; ++j) {
            const int rb = wc * 64 + j * 32 + ml;
            bS[j] = *(const bf16x8*)&Bt[c][rb * 64 + ((((ks * 2 + h) + (rb & 7)) & 7) * 8)];
        }
    };
    auto mfma8 = [&](bf16x8* aS, bf16x8* bS) {
        __builtin_amdgcn_s_setprio(1);
        #pragma unroll
        for (int i = 0; i < 4; ++i)
            #pragma unroll
            for (int j = 0; j < 2; ++j)
                acc[i][j] = __builtin_amdgcn_mfma_f32_32x32x16_bf16(
                    aS[i], bS[j], acc[i][j], 0, 0, 0);
        __builtin_amdgcn_s_setprio(0);
    };

    // one K-tile, buf c; stages tile t+1 into c^1; leaves set0 = next ks0 frags
    auto body = [&](int c) {
        // p0: MFMA ks0 (set0); read ks1 -> set1; stage next-tile A
        stageA(c ^ 1); dsr(1, c, a1, b1);
        SCHED0(); BAR(); LGKM(6); SCHED0(); mfma8(a0, b0); SCHED0(); BAR();
        // p1: MFMA ks1 (set1); read ks2 -> set0; stage next-tile B
        stageB(c ^ 1); dsr(2, c, a0, b0);
        SCHED0(); BAR(); LGKM(6); SCHED0(); mfma8(a1, b1); SCHED0(); BAR();
        // p2: MFMA ks2 (set0); read ks3 -> set1
        dsr(3, c, a1, b1);
        SCHED0(); BAR(); LGKM(6); SCHED0(); mfma8(a0, b0); SCHED0(); BAR();
        // p3: next tile resident (counted-exact vmcnt: only its 8 loads are
        // outstanding, 2-3 phases old); MFMA ks3 (set1); read next ks0 -> set0
        VMCNT(0); BAR();
        dsr(0, c ^ 1, a0, b0);
        LGKM(6); SCHED0(); mfma8(a1, b1); SCHED0(); BAR();
    };

    // prologue: tile 0 -> buf 0; cold drain; first frag set
    stageA(0); stageB(0);
    VMCNT(0); BAR();
    dsr(0, 0, a0, b0);

    // tiles 0..14 (body stages tiles 1..15); tail tile 15 from buf 1
    #pragma unroll 1
    for (int it = 0; it < 7; ++it) { body(0); body(1); }
    body(0);   // t=14: stages tile 15 -> buf1, leaves set0 = tile15 ks0

    dsr(1, 1, a1, b1); LGKM(6); SCHED0(); mfma8(a0, b0);
    dsr(2, 1, a0, b0); LGKM(6); SCHED0(); mfma8(a1, b1);
    dsr(3, 1, a1, b1); LGKM(6); SCHED0(); mfma8(a0, b0);
    LGKM(0); SCHED0(); mfma8(a1, b1);

    // epilogue: C/D layout col=ml (n), row=(reg&3)+8*(reg>>2)+4*h (m)
    #pragma unroll
    for (int j = 0; j < 2; ++j) {
        const int n = n0 + wc * 64 + j * 32 + ml;
        const float bj = bias[n];
        #pragma unroll
        for (int i = 0; i < 4; ++i) {
            const int mbase = m0 + wr * 128 + i * 32 + 4 * h;
            #pragma unroll
            for (int reg = 0; reg < 16; ++reg) {
                const int m = mbase + (reg & 3) + 8 * (reg >> 2);
                C[(size_t)m * N_DIM + n] = gelu_fast(acc[i][j][reg] + bj);
            }
        }
    }
}

extern "C" void kernel_launch(void* const* d_in, const int* in_sizes, int n_in,
                              void* d_out, int out_size, void* d_ws, size_t ws_size,
                              hipStream_t stream) {
    const float* x556 = (const float*)d_in[0];
    const float* x570 = (const float*)d_in[1];
    const float* gam  = (const float*)d_in[2];
    const float* bet  = (const float*)d_in[3];
    const float* Wlin = (const float*)d_in[4];
    const float* blin = (const float*)d_in[5];
    float* out = (float*)d_out;

    unsigned short* xn = (unsigned short*)d_ws;            // 25.69 MB
    unsigned short* wb = xn + (size_t)M_DIM * K_DIM;       // 8.39 MB

    pre_fused<<<M_DIM / 4 + 1024, 256, 0, stream>>>(x556, x570, gam, bet, Wlin, xn, wb);
    gemm_bias_gelu<<<dim3(M_DIM / 256, N_DIM / 256), 512, 0, stream>>>(xn, wb, blin, out);
}